// Round 20
// baseline (298.234 us; speedup 1.0000x reference)
//
#include <hip/hip_runtime.h>
#include <hip/hip_bf16.h>
#include <hip/hip_fp16.h>
#include <math.h>

#define NNODES 50000
#define NEDGES 800000
#define FIN 128
#define FH 256
#define NG 64
#define NC 64
#define SCAN_NB ((NNODES + 255) / 256)       // 196
#define NP 50176              // K padded to 196*256
#define QSK 196               // split-K blocks for qsum (NP/256)
#define DEG_BLOCKS ((NEDGES + 255) / 256)    // 3125
#define SPLITX_ITEMS (NNODES * FIN / 4)      // 1.6M
#define SPLITX_BLOCKS ((SPLITX_ITEMS + 255) / 256)   // 6250
#define WTZ_ITEMS (NG * NP / 4)              // 802816
#define WTZ_BLOCKS ((WTZ_ITEMS + 255) / 256)         // 3136
#define GEMM_MB ((NNODES + 127) / 128)       // 391
#define GEMM_BLKS (GEMM_MB * 2)              // 782
#define CVT_ITEMS (NG * NP / 4)
#define CVT_BLOCKS ((CVT_ITEMS + 255) / 256) // 3136

typedef unsigned short bhalf;
typedef __attribute__((ext_vector_type(8))) short bf16x8;
typedef __attribute__((ext_vector_type(4))) float f32x4;
typedef __attribute__((ext_vector_type(4))) unsigned short u16x4;

__device__ inline bhalf f2bf_rn(float f) {
    unsigned int u = __float_as_uint(f);
    u += 0x7FFFu + ((u >> 16) & 1u);      // round-to-nearest-even
    return (bhalf)(u >> 16);
}
__device__ inline float bf2f(bhalf h) { return __uint_as_float(((unsigned int)h) << 16); }
__device__ inline float2 bfpair(unsigned int u) {   // [lo16, hi16] -> two floats
    return make_float2(__uint_as_float(u << 16), __uint_as_float(u & 0xFFFF0000u));
}
__device__ inline float edec_norm(unsigned int ed) {  // low 16 bits = f16 norm
    return __half2float(__ushort_as_half((unsigned short)(ed & 0xFFFFu)));
}

// ---------------- degree/rank + x->bf16 + wt zeroing (3 block ranges) ----------------
// wt is first written 2 dispatches later (scan_offsets) -> zeroing here is safe.

__global__ void degree_splitx_kernel(const int* __restrict__ dst, int* __restrict__ degi,
                                     int* __restrict__ rank, const float* __restrict__ x,
                                     bhalf* __restrict__ xb, float* __restrict__ wt) {
    int b = blockIdx.x;
    if (b < DEG_BLOCKS) {
        int e = b * 256 + threadIdx.x;
        if (e < NEDGES) rank[e] = atomicAdd(&degi[dst[e]], 1);
    } else if (b < DEG_BLOCKS + SPLITX_BLOCKS) {
        int i = (b - DEG_BLOCKS) * 256 + threadIdx.x;
        if (i < SPLITX_ITEMS) {
            float4 v = *reinterpret_cast<const float4*>(&x[i * 4]);
            u16x4 o = {f2bf_rn(v.x), f2bf_rn(v.y), f2bf_rn(v.z), f2bf_rn(v.w)};
            *reinterpret_cast<u16x4*>(&xb[i * 4]) = o;
        }
    } else {
        int i = (b - DEG_BLOCKS - SPLITX_BLOCKS) * 256 + threadIdx.x;
        if (i < WTZ_ITEMS) {
            f32x4 zr = {0.f, 0.f, 0.f, 0.f};
            *reinterpret_cast<f32x4*>(&wt[i * 4]) = zr;
        }
    }
}

// ---------------- one-shot scan: block-redundant prefix + local scan + dinv + wt self + split_w ----
// Block b sums degi[0..b*256) itself (L2-hot coalesced) -> no second-level kernel needed.

__global__ __launch_bounds__(256)
void scan_offsets_kernel(const int* __restrict__ degi, int* __restrict__ row_start,
                         float* __restrict__ dinv, const int* __restrict__ batch,
                         float* __restrict__ wt, const float* __restrict__ W1,
                         bhalf* __restrict__ w1t, int Nn) {
    __shared__ int red[256];
    __shared__ int s[256];
    const int b = blockIdx.x;
    const int t = threadIdx.x;
    const int base = b * 256;
    // phase 1: prefix = sum of degi[0 .. base)
    int acc = 0;
    for (int i = t; i < base; i += 256) acc += degi[i];
    red[t] = acc;
    __syncthreads();
#pragma unroll
    for (int off = 128; off > 0; off >>= 1) {
        if (t < off) red[t] += red[t + off];
        __syncthreads();
    }
    int prefix = red[0];
    // phase 2: local inclusive scan of this block's degi slice
    int i = base + t;
    int v = (i < Nn) ? degi[i] : 0;
    s[t] = v;
    __syncthreads();
#pragma unroll
    for (int off = 1; off < 256; off <<= 1) {
        int tv = (t >= off) ? s[t - off] : 0;
        __syncthreads();
        s[t] += tv;
        __syncthreads();
    }
    if (i < Nn) {
        row_start[i] = prefix + s[t] - v;       // exclusive prefix
        float sn = rsqrtf((float)v + 1.0f);
        dinv[i] = sn;
        atomicAdd(&wt[(size_t)batch[i] * NP + i], sn * sn);
    }
    if (i < FIN * 256) {                        // fused split_w: W1[K][256] -> w1t[256][K]
        int k = i >> 8, n = i & 255;
        w1t[n * FIN + k] = f2bf_rn(W1[i]);
    }
}

// ---------------- edge placement + pooling-weight build (merged, rank-based) ----------------

__global__ void edge_place_kernel(const int* __restrict__ src, const int* __restrict__ dst,
                                  const int* __restrict__ row_start, const int* __restrict__ rank,
                                  const float* __restrict__ dinv, const int* __restrict__ batch,
                                  unsigned int* __restrict__ edata, float* __restrict__ wt, int E) {
    int e = blockIdx.x * blockDim.x + threadIdx.x;
    if (e >= E) return;
    int s = src[e], d = dst[e];
    int pos = row_start[d] + rank[e];
    float nm = dinv[s] * dinv[d];
    unsigned short hb = __half_as_ushort(__float2half(nm));
    edata[pos] = ((unsigned int)s << 16) | (unsigned int)hb;
    atomicAdd(&wt[(size_t)batch[d] * NP + s], nm);
}

// ---------------- CSR gather, 128 bf16 feats: z[n] = bf16(sum + x[n]*sn), unroll-4 ----------------

__global__ __launch_bounds__(256)
void gather128_kernel(const bhalf* __restrict__ xb, const unsigned int* __restrict__ edata,
                      const int* __restrict__ row_start, const int* __restrict__ degi,
                      const float* __restrict__ dinv, bhalf* __restrict__ z, int Nn) {
    int node = blockIdx.x * 4 + (threadIdx.x >> 6);
    if (node >= Nn) return;
    int lane = threadIdx.x & 63;
    int st = row_start[node];
    int cnt = degi[node];
    float ax = 0.0f, ay = 0.0f;
    int j = 0;
    for (; j + 3 < cnt; j += 4) {
        unsigned int e0 = edata[st + j],     e1 = edata[st + j + 1];
        unsigned int e2 = edata[st + j + 2], e3 = edata[st + j + 3];
        float2 v0 = bfpair(*reinterpret_cast<const unsigned int*>(&xb[(size_t)(e0 >> 16) * FIN + lane * 2]));
        float2 v1 = bfpair(*reinterpret_cast<const unsigned int*>(&xb[(size_t)(e1 >> 16) * FIN + lane * 2]));
        float2 v2 = bfpair(*reinterpret_cast<const unsigned int*>(&xb[(size_t)(e2 >> 16) * FIN + lane * 2]));
        float2 v3 = bfpair(*reinterpret_cast<const unsigned int*>(&xb[(size_t)(e3 >> 16) * FIN + lane * 2]));
        float n0 = edec_norm(e0), n1 = edec_norm(e1), n2 = edec_norm(e2), n3 = edec_norm(e3);
        ax += v0.x * n0 + v1.x * n1 + v2.x * n2 + v3.x * n3;
        ay += v0.y * n0 + v1.y * n1 + v2.y * n2 + v3.y * n3;
    }
    for (; j < cnt; j++) {
        unsigned int e0 = edata[st + j];
        float2 v0 = bfpair(*reinterpret_cast<const unsigned int*>(&xb[(size_t)(e0 >> 16) * FIN + lane * 2]));
        float n0 = edec_norm(e0);
        ax += v0.x * n0; ay += v0.y * n0;
    }
    float sn = dinv[node];
    sn *= sn;
    float2 xv = bfpair(*reinterpret_cast<const unsigned int*>(&xb[(size_t)node * FIN + lane * 2]));
    ushort2 o = {f2bf_rn(ax + xv.x * sn), f2bf_rn(ay + xv.y * sn)};
    *reinterpret_cast<ushort2*>(&z[(size_t)node * FIN + lane * 2]) = o;
}

// ---------------- MFMA bf16 GEMM (transposed out) + fused cvt_wt (block ranges) ----------------

__global__ __launch_bounds__(256)
void gemm_cvt_kernel(const bhalf* __restrict__ A, const bhalf* __restrict__ Bt,
                     const float* __restrict__ bias, bhalf* __restrict__ h1t,
                     const float* __restrict__ wt, bhalf* __restrict__ wthi,
                     bhalf* __restrict__ wtlo, int M, int Kp) {
    __shared__ bhalf As[128 * 72];   // rows x (64+8 pad): 144 B row stride
    __shared__ bhalf Bs[128 * 72];
    if (blockIdx.x >= GEMM_BLKS) {
        int i = (blockIdx.x - GEMM_BLKS) * 256 + threadIdx.x;
        if (i < CVT_ITEMS) {
            float4 v = *reinterpret_cast<const float4*>(&wt[i * 4]);
            u16x4 hi = {f2bf_rn(v.x), f2bf_rn(v.y), f2bf_rn(v.z), f2bf_rn(v.w)};
            u16x4 lo = {f2bf_rn(v.x - bf2f(hi.x)), f2bf_rn(v.y - bf2f(hi.y)),
                        f2bf_rn(v.z - bf2f(hi.z)), f2bf_rn(v.w - bf2f(hi.w))};
            *reinterpret_cast<u16x4*>(&wthi[i * 4]) = hi;
            *reinterpret_cast<u16x4*>(&wtlo[i * 4]) = lo;
        }
        return;
    }
    const int tid  = threadIdx.x;
    const int lane = tid & 63;
    const int wave = tid >> 6;
    const int quad = lane >> 4;
    const int l15  = lane & 15;
    const int wm = (wave & 1) * 64;
    const int wn = (wave >> 1) * 64;
    const int bm = (blockIdx.x >> 1) * 128;
    const int bn = (blockIdx.x & 1) * 128;

    f32x4 acc[4][4] = {};

    for (int k0 = 0; k0 < Kp; k0 += 64) {
#pragma unroll
        for (int i = 0; i < 4; i++) {
            int chunk = tid + i * 256;           // 1024 chunks of 8 bf16
            int r = chunk >> 3, c16 = chunk & 7;
            int gm = bm + r;
            float4 va = make_float4(0.f, 0.f, 0.f, 0.f);
            if (gm < M) va = *reinterpret_cast<const float4*>(&A[(size_t)gm * Kp + k0 + c16 * 8]);
            *reinterpret_cast<float4*>(&As[r * 72 + c16 * 8]) = va;
            float4 vb = *reinterpret_cast<const float4*>(&Bt[(size_t)(bn + r) * Kp + k0 + c16 * 8]);
            *reinterpret_cast<float4*>(&Bs[r * 72 + c16 * 8]) = vb;
        }
        __syncthreads();
#pragma unroll
        for (int kk = 0; kk < 64; kk += 32) {
            bf16x8 af[4], bfr[4];
#pragma unroll
            for (int mi = 0; mi < 4; mi++)
                af[mi] = *reinterpret_cast<const bf16x8*>(&As[(wm + mi * 16 + l15) * 72 + kk + quad * 8]);
#pragma unroll
            for (int ni = 0; ni < 4; ni++)
                bfr[ni] = *reinterpret_cast<const bf16x8*>(&Bs[(wn + ni * 16 + l15) * 72 + kk + quad * 8]);
#pragma unroll
            for (int mi = 0; mi < 4; mi++)
#pragma unroll
                for (int ni = 0; ni < 4; ni++)
                    acc[mi][ni] = __builtin_amdgcn_mfma_f32_16x16x32_bf16(af[mi], bfr[ni], acc[mi][ni], 0, 0, 0);
        }
        __syncthreads();
    }

    // epilogue: C/D col = lane&15, row = quad*4 + r. Write transposed: h1t[col][row0..row0+3].
#pragma unroll
    for (int mi = 0; mi < 4; mi++) {
        int row0 = bm + wm + mi * 16 + quad * 4;
#pragma unroll
        for (int ni = 0; ni < 4; ni++) {
            int col = bn + wn + ni * 16 + l15;
            float bv = bias[col];
            u16x4 o;
#pragma unroll
            for (int r = 0; r < 4; r++) {
                float v = acc[mi][ni][r] + bv;
                v = 0.5f * v * (1.0f + erff(v * 0.70710678118654752f));
                o[r] = f2bf_rn(v);
            }
            *reinterpret_cast<u16x4*>(&h1t[(size_t)col * NP + row0]) = o;
        }
    }
}

// ---------------- qsum MFMA: qpart[b][g][k] = h1t @ {wthi,wtlo}^T over K chunk ----------------

__global__ __launch_bounds__(256)
void qsum_mfma_kernel(const bhalf* __restrict__ h1t, const bhalf* __restrict__ wthi,
                      const bhalf* __restrict__ wtlo, float* __restrict__ qpart) {
    const int tid  = threadIdx.x;
    const int lane = tid & 63;
    const int wave = tid >> 6;
    const int quad = lane >> 4;
    const int l15  = lane & 15;
    const int m0 = wave * 64;
    const size_t kbase = (size_t)blockIdx.x * 256 + quad * 8;
    f32x4 acc[4][4] = {};
#pragma unroll
    for (int ks = 0; ks < 8; ks++) {
        size_t k0 = kbase + ks * 32;
        bf16x8 af[4], bh[4], bl[4];
#pragma unroll
        for (int mi = 0; mi < 4; mi++)
            af[mi] = *reinterpret_cast<const bf16x8*>(&h1t[(size_t)(m0 + mi * 16 + l15) * NP + k0]);
#pragma unroll
        for (int ni = 0; ni < 4; ni++) {
            bh[ni] = *reinterpret_cast<const bf16x8*>(&wthi[(size_t)(ni * 16 + l15) * NP + k0]);
            bl[ni] = *reinterpret_cast<const bf16x8*>(&wtlo[(size_t)(ni * 16 + l15) * NP + k0]);
        }
#pragma unroll
        for (int mi = 0; mi < 4; mi++)
#pragma unroll
            for (int ni = 0; ni < 4; ni++) {
                acc[mi][ni] = __builtin_amdgcn_mfma_f32_16x16x32_bf16(af[mi], bh[ni], acc[mi][ni], 0, 0, 0);
                acc[mi][ni] = __builtin_amdgcn_mfma_f32_16x16x32_bf16(af[mi], bl[ni], acc[mi][ni], 0, 0, 0);
            }
    }
    float* qp = &qpart[(size_t)blockIdx.x * NG * FH];
#pragma unroll
    for (int mi = 0; mi < 4; mi++) {
        int row0 = m0 + mi * 16 + quad * 4;          // k-dim 0..255 (4 consecutive)
#pragma unroll
        for (int ni = 0; ni < 4; ni++) {
            int col = ni * 16 + l15;                 // g-dim 0..63
            f32x4 o = {acc[mi][ni][0], acc[mi][ni][1], acc[mi][ni][2], acc[mi][ni][3]};
            *reinterpret_cast<f32x4*>(&qp[(size_t)col * FH + row0]) = o;
        }
    }
}

// ---------------- fused head: q-reduce + pooled = (q@W2)/cnt + b2 ; out = pooled@Wfc + bfc ----------------

__global__ __launch_bounds__(256)
void p2fc_kernel(const float* __restrict__ qpart, const float* __restrict__ W2,
                 const float* __restrict__ b2, const int* __restrict__ batch,
                 const float* __restrict__ Wfc, const float* __restrict__ bfc,
                 float* __restrict__ out) {
    __shared__ float qg[FH];
    __shared__ float ps[FH];
    int g = blockIdx.x;
    int t = threadIdx.x;
    float s = 0.0f;
    for (int b = 0; b < QSK; b++)                    // coalesced: consecutive t -> consecutive k
        s += qpart[(size_t)b * NG * FH + (size_t)g * FH + t];
    qg[t] = s;
    int lo = 0, hi = NNODES;
    while (lo < hi) { int m = (lo + hi) >> 1; if (batch[m] < g) lo = m + 1; else hi = m; }
    int a = lo;
    lo = 0; hi = NNODES;
    while (lo < hi) { int m = (lo + hi) >> 1; if (batch[m] < g + 1) lo = m + 1; else hi = m; }
    float inv = 1.0f / fmaxf((float)(lo - a), 1.0f);
    __syncthreads();
    float acc = 0.0f;
    for (int k = 0; k < FH; k++)
        acc += qg[k] * W2[k * FH + t];
    ps[t] = acc * inv + b2[t];
    __syncthreads();
    if (t < NC) {
        float a2 = 0.0f;
        for (int cc = 0; cc < FH; cc++)
            a2 += ps[cc] * Wfc[cc * NC + t];
        out[g * NC + t] = a2 + bfc[t];
    }
}

// ---------------- launch ----------------

extern "C" void kernel_launch(void* const* d_in, const int* in_sizes, int n_in,
                              void* d_out, int out_size, void* d_ws, size_t ws_size,
                              hipStream_t stream) {
    const float* x    = (const float*)d_in[0];
    const int*   ei   = (const int*)d_in[1];
    const int*   batch= (const int*)d_in[2];
    const float* W1   = (const float*)d_in[3];
    const float* b1   = (const float*)d_in[4];
    const float* W2   = (const float*)d_in[5];
    const float* b2   = (const float*)d_in[6];
    const float* Wfc  = (const float*)d_in[7];
    const float* bfc  = (const float*)d_in[8];
    float* out = (float*)d_out;

    const int* src = ei;
    const int* dst = ei + NEDGES;

    // workspace (~97 MB):
    bhalf* xb        = (bhalf*)d_ws;                       // [N,128] bf16 (12.8 MB)
    bhalf* zb        = xb + (size_t)NNODES * FIN;          // [N,128] bf16 (12.8 MB)
    bhalf* h1t       = zb + (size_t)NNODES * FIN;          // [256,NP] bf16 (25.7 MB)
    unsigned int* edata = (unsigned int*)(h1t + (size_t)FH * NP);  // [E] packed (3.2 MB)
    int*   rank      = (int*)(edata + NEDGES);             // [E] (3.2 MB)
    int*   row_start = rank + NEDGES;                      // [N]
    float* dinv      = (float*)(row_start + NNODES);       // [N]
    bhalf* w1t       = (bhalf*)(dinv + NNODES);            // [256,128] bf16
    bhalf* wthi      = w1t + 256 * FIN;                    // [64,NP] bf16 (6.4 MB)
    bhalf* wtlo      = wthi + (size_t)NG * NP;             // [64,NP] bf16 (6.4 MB)
    float* qpart     = (float*)(wtlo + (size_t)NG * NP);   // [QSK,64,256] f32, [g][k] (12.85 MB)
    float* wt        = qpart + (size_t)QSK * NG * FH;      // [64,NP] f32 (zeroed in-kernel)
    int*   degi      = (int*)(wt + (size_t)NG * NP);       // [N] (memset)

    (void)hipMemsetAsync(degi, 0, (size_t)NNODES * 4, stream);

    // ---- CSR build + norms + pooling weights (3 dispatches) ----
    degree_splitx_kernel<<<DEG_BLOCKS + SPLITX_BLOCKS + WTZ_BLOCKS, 256, 0, stream>>>(
        dst, degi, rank, x, xb, wt);
    scan_offsets_kernel<<<SCAN_NB, 256, 0, stream>>>(degi, row_start, dinv, batch,
                                                     wt, W1, w1t, NNODES);
    edge_place_kernel<<<(NEDGES + 255) / 256, 256, 0, stream>>>(src, dst, row_start, rank,
                                                                dinv, batch, edata, wt, NEDGES);

    // conv1 (aggregate-first): z = bf16(Ahat*x) ; h1t = bf16(gelu(z@W1 + b1))^T ; cvt_wt fused
    gather128_kernel<<<(NNODES + 3) / 4, 256, 0, stream>>>(xb, edata, row_start, degi,
                                                           dinv, zb, NNODES);
    gemm_cvt_kernel<<<GEMM_BLKS + CVT_BLOCKS, 256, 0, stream>>>(zb, w1t, b1, h1t,
                                                                wt, wthi, wtlo, NNODES, FIN);

    // conv2 + pool collapsed via MFMA: qT = h1t @ wt^T ; out = ((q@W2)/cnt + b2)@Wfc + bfc
    qsum_mfma_kernel<<<QSK, 256, 0, stream>>>(h1t, wthi, wtlo, qpart);
    p2fc_kernel<<<NG, FH, 0, stream>>>(qpart, W2, b2, batch, Wfc, bfc, out);
}